// Round 1
// baseline (141.504 us; speedup 1.0000x reference)
//
#include <hip/hip_runtime.h>
#include <math.h>

// Problem constants (from setup_inputs):
//   original: [B=4, C=3, H=512, W=512] f32
//   degraded: [B=4, N-1=7, C=3, H=512, W=512] f32
//   logits:   [N=8, LH=32, LW=32] f32
//   topk:     int scalar (=2)
// out: [4,3,512,512] f32
//
// out[b,c,h,w] = sum_n stacked[b,n,c,h,w] * wfin[n,h,w]
// where wfin = renormalized top-k mask of softmax(bilinear_upsample(logits)).

#define HW_ (512 * 512)

__global__ __launch_bounds__(256) void rain_combine_kernel(
    const float* __restrict__ orig,    // [4,3,512,512]
    const float* __restrict__ deg,     // [4,7,3,512,512]
    const float* __restrict__ logits,  // [8,32,32]
    const int* __restrict__ topk_p,
    float* __restrict__ out)           // [4,3,512,512]
{
    const int p = blockIdx.x * 256 + threadIdx.x;   // pixel id in [0, 512*512)
    const int h = p >> 9;
    const int w = p & 511;

    // ---- bilinear upsample coords: half-pixel centers, 16x upscale ----
    // input coord = (i + 0.5) / 16 - 0.5 ; edge handling == clamp (JAX
    // normalizes the truncated triangle kernel to 1 at borders, which for
    // 2-tap linear equals clamping both taps to the edge texel).
    const float yc = (h + 0.5f) * 0.0625f - 0.5f;
    const float xc = (w + 0.5f) * 0.0625f - 0.5f;
    const float yf = floorf(yc), xf = floorf(xc);
    const float fy = yc - yf,   fx = xc - xf;
    const int y0 = (int)yf, x0 = (int)xf;
    const int y0c = max(y0, 0),     x0c = max(x0, 0);
    const int y1c = min(y0 + 1, 31), x1c = min(x0 + 1, 31);
    const float w00 = (1.f - fy) * (1.f - fx);
    const float w01 = (1.f - fy) * fx;
    const float w10 = fy * (1.f - fx);
    const float w11 = fy * fx;

    const int o00 = y0c * 32 + x0c;
    const int o01 = y0c * 32 + x1c;
    const int o10 = y1c * 32 + x0c;
    const int o11 = y1c * 32 + x1c;

    float up[8];
    #pragma unroll
    for (int n = 0; n < 8; ++n) {
        const float* Lb = logits + n * 1024;
        up[n] = w00 * Lb[o00] + w01 * Lb[o01] + w10 * Lb[o10] + w11 * Lb[o11];
    }

    // ---- softmax over n (TEMPERATURE = 1) ----
    float mx = up[0];
    #pragma unroll
    for (int n = 1; n < 8; ++n) mx = fmaxf(mx, up[n]);
    float e[8];
    float s = 0.f;
    #pragma unroll
    for (int n = 0; n < 8; ++n) { e[n] = expf(up[n] - mx); s += e[n]; }
    float wgt[8];
    #pragma unroll
    for (int n = 0; n < 8; ++n) wgt[n] = e[n] / s;

    // ---- k-th largest (rank-based, tie-exact vs jax.lax.top_k) ----
    const int k = *topk_p;   // = 2
    float kth = -INFINITY;
    #pragma unroll
    for (int n = 0; n < 8; ++n) {
        int gt = 0, ge = 0;
        #pragma unroll
        for (int j = 0; j < 8; ++j) {
            gt += (wgt[j] >  wgt[n]);
            ge += (wgt[j] >= wgt[n]);
        }
        // wgt[n] is the k-th largest iff fewer than k strictly above it and
        // at least k at-or-above it (handles duplicates like top_k does).
        if (gt < k && ge >= k) kth = wgt[n];
    }

    // ---- keep mask + renorm sum (ascending n, matching jnp.sum order) ----
    unsigned keep = 0u;
    float S = 0.f;
    #pragma unroll
    for (int n = 0; n < 8; ++n) {
        if (wgt[n] >= kth) { keep |= (1u << n); S += wgt[n]; }
    }

    // ---- weighted combine: only load kept branches (typically 2 of 8) ----
    float acc[12];
    #pragma unroll
    for (int i = 0; i < 12; ++i) acc[i] = 0.f;

    #pragma unroll
    for (int n = 0; n < 8; ++n) {
        if (keep & (1u << n)) {         // exec-masked; whole block skipped if no lane keeps n
            const float wn = wgt[n] / S;
            const float* base = (n == 0) ? (orig + p)
                                         : (deg + (size_t)(n - 1) * 3 * HW_ + p);
            const int bstr = (n == 0) ? 3 * HW_ : 21 * HW_;
            #pragma unroll
            for (int b = 0; b < 4; ++b) {
                #pragma unroll
                for (int c = 0; c < 3; ++c) {
                    acc[b * 3 + c] += wn * base[(size_t)b * bstr + (size_t)c * HW_];
                }
            }
        }
    }

    #pragma unroll
    for (int b = 0; b < 4; ++b) {
        #pragma unroll
        for (int c = 0; c < 3; ++c) {
            out[(size_t)(b * 3 + c) * HW_ + p] = acc[b * 3 + c];
        }
    }
}

extern "C" void kernel_launch(void* const* d_in, const int* in_sizes, int n_in,
                              void* d_out, int out_size, void* d_ws, size_t ws_size,
                              hipStream_t stream) {
    const float* orig   = (const float*)d_in[0];
    const float* deg    = (const float*)d_in[1];
    const float* logits = (const float*)d_in[2];
    const int*   topk   = (const int*)d_in[3];
    float* out = (float*)d_out;

    const int pixels = 512 * 512;
    rain_combine_kernel<<<dim3(pixels / 256), dim3(256), 0, stream>>>(
        orig, deg, logits, topk, out);
}